// Round 3
// baseline (7027.241 us; speedup 1.0000x reference)
//
#include <hip/hip_runtime.h>

typedef unsigned short u16;
typedef unsigned int   u32;
typedef unsigned long long u64;
typedef __attribute__((ext_vector_type(4))) float f32x4;
typedef __attribute__((ext_vector_type(8))) short short8;
typedef __attribute__((ext_vector_type(8))) __bf16 bf16x8v;

// ---------- bf16 helpers (manual, RNE) ----------
__device__ __forceinline__ float bf2f(u16 v) { return __uint_as_float(((u32)v) << 16); }
__device__ __forceinline__ u16 f2bf(float f) {
    u32 u = __float_as_uint(f);
    u32 r = (u + 0x7fffu + ((u >> 16) & 1u)) >> 16;
    return (u16)r;
}
__device__ __forceinline__ float sigm(float x) { return 1.f / (1.f + __expf(-x)); }
__device__ __forceinline__ float tanh_f(float x) { return 1.f - 2.f / (__expf(2.f * x) + 1.f); }

// ---------- MFMA wrapper: works whether builtin wants short8 or v8bf16 ----------
template <class A>
__device__ __forceinline__ auto try_mfma(A a, A b, f32x4 c, int)
    -> decltype(__builtin_amdgcn_mfma_f32_16x16x32_bf16(a, b, c, 0, 0, 0)) {
    return __builtin_amdgcn_mfma_f32_16x16x32_bf16(a, b, c, 0, 0, 0);
}
template <class A>
__device__ __forceinline__ f32x4 try_mfma(A a, A b, f32x4 c, long) {
    return __builtin_amdgcn_mfma_f32_16x16x32_bf16(
        __builtin_bit_cast(bf16x8v, a), __builtin_bit_cast(bf16x8v, b), c, 0, 0, 0);
}
__device__ __forceinline__ f32x4 MFMA(short8 a, short8 b, f32x4 c) { return try_mfma(a, b, c, 0); }

// B=64, S=1024, H=512 fixed.

// ---------- prep: bf16 weight copies / transposes / combined bias ----------
__global__ void k_prep(const float* __restrict__ w_ih, const float* __restrict__ w_hh,
                       const float* __restrict__ b_ih, const float* __restrict__ b_hh,
                       const float* __restrict__ w1, const float* __restrict__ w2,
                       u16* __restrict__ wihb, u16* __restrict__ whhb,
                       u16* __restrict__ w1t, u16* __restrict__ w2t, float* __restrict__ biasc) {
    for (u32 i = blockIdx.x * blockDim.x + threadIdx.x; i < 3147776u; i += gridDim.x * blockDim.x) {
        if (i < 1048576u) { wihb[i] = f2bf(w_ih[i]); }
        else if (i < 2097152u) { u32 j = i - 1048576u; whhb[j] = f2bf(w_hh[j]); }
        else if (i < 2621440u) { u32 j = i - 2097152u; u32 n = j >> 9,  k = j & 511u;  w1t[j] = f2bf(w1[k * 1024u + n]); }
        else if (i < 3145728u) { u32 j = i - 2621440u; u32 n = j >> 10, k = j & 1023u; w2t[j] = f2bf(w2[k * 512u + n]); }
        else { u32 j = i - 3145728u; biasc[j] = b_ih[j] + b_hh[j]; }
    }
}

// ---------- init: zero tagged exchange buffer (tag0 == h(0)=0) ----------
__global__ void k_init(u32* __restrict__ h_ex) {
    u32 i = blockIdx.x * blockDim.x + threadIdx.x;
    if (i < 65536u) h_ex[i] = 0u;
}

// ---------- LayerNorm: one wave per row of 512 ----------
__global__ __launch_bounds__(256) void k_pre_ln(const float* __restrict__ x,
                                                const float* __restrict__ g, const float* __restrict__ b,
                                                u16* __restrict__ out) {
    const int row = blockIdx.x * 4 + (threadIdx.x >> 6);
    const int lane = threadIdx.x & 63;
    const float* xr = x + (size_t)row * 512 + lane * 8;
    float v[8];
    *(float4*)(v)     = *(const float4*)(xr);
    *(float4*)(v + 4) = *(const float4*)(xr + 4);
    float s = 0.f, q = 0.f;
#pragma unroll
    for (int e = 0; e < 8; ++e) { s += v[e]; q += v[e] * v[e]; }
#pragma unroll
    for (int o = 32; o; o >>= 1) { s += __shfl_xor(s, o); q += __shfl_xor(q, o); }
    float mu = s * (1.f / 512.f);
    float rs = rsqrtf(q * (1.f / 512.f) - mu * mu + 1e-5f);
    short8 ov;
#pragma unroll
    for (int e = 0; e < 8; ++e) {
        int cidx = lane * 8 + e;
        ov[e] = (short)f2bf((v[e] - mu) * rs * g[cidx] + b[cidx]);
    }
    *(short8*)(out + (size_t)row * 512 + lane * 8) = ov;
}

__global__ __launch_bounds__(256) void k_res_ln(const float* __restrict__ x, const u16* __restrict__ r,
                                                const float* __restrict__ g, const float* __restrict__ b,
                                                u16* __restrict__ out) {
    const int row = blockIdx.x * 4 + (threadIdx.x >> 6);
    const int lane = threadIdx.x & 63;
    const float* xr = x + (size_t)row * 512 + lane * 8;
    short8 rv = *(const short8*)(r + (size_t)row * 512 + lane * 8);
    float v[8];
    *(float4*)(v)     = *(const float4*)(xr);
    *(float4*)(v + 4) = *(const float4*)(xr + 4);
#pragma unroll
    for (int e = 0; e < 8; ++e) v[e] += bf2f((u16)rv[e]);
    float s = 0.f, q = 0.f;
#pragma unroll
    for (int e = 0; e < 8; ++e) { s += v[e]; q += v[e] * v[e]; }
#pragma unroll
    for (int o = 32; o; o >>= 1) { s += __shfl_xor(s, o); q += __shfl_xor(q, o); }
    float mu = s * (1.f / 512.f);
    float rs = rsqrtf(q * (1.f / 512.f) - mu * mu + 1e-5f);
    short8 ov;
#pragma unroll
    for (int e = 0; e < 8; ++e) {
        int cidx = lane * 8 + e;
        ov[e] = (short)f2bf((v[e] - mu) * rs * g[cidx] + b[cidx]);
    }
    *(short8*)(out + (size_t)row * 512 + lane * 8) = ov;
}

// ---------- GEMM (B^T layout): C[m,n] = sum_k A[m,k]*B[n,k] (+bias, epilogues) ----------
template <int KD, int EPI>
__global__ __launch_bounds__(256, 2)
void k_gemm(const u16* __restrict__ A, const u16* __restrict__ B,
            const float* __restrict__ bias, u16* __restrict__ Cb, float* __restrict__ Cf,
            const float* __restrict__ Xres, const u16* __restrict__ Rres, int N) {
    __shared__ __align__(16) u16 At[128 * 64];
    __shared__ __align__(16) u16 Bt[128 * 64];
    const int tid = threadIdx.x;
    const int lane = tid & 63, wv = tid >> 6;
    const int m0 = blockIdx.y << 7, n0 = blockIdx.x << 7;
    const int wm = (wv >> 1) << 6, wn = (wv & 1) << 6;
    f32x4 acc[4][4] = {};
    const int r_st = tid >> 3, kb_st = tid & 7;

    for (int k0 = 0; k0 < KD; k0 += 64) {
#pragma unroll
        for (int rnd = 0; rnd < 4; ++rnd) {
            int rr = r_st + rnd * 32;
            short8 va = *(const short8*)(A + (size_t)(m0 + rr) * KD + (k0 + kb_st * 8));
            short8 vb = *(const short8*)(B + (size_t)(n0 + rr) * KD + (k0 + kb_st * 8));
            int byt = rr * 128 + ((kb_st * 16) ^ ((rr & 7) << 4));
            *(short8*)((char*)At + byt) = va;
            *(short8*)((char*)Bt + byt) = vb;
        }
        __syncthreads();
#pragma unroll
        for (int ks = 0; ks < 2; ++ks) {
            short8 af[4], bf[4];
#pragma unroll
            for (int mt = 0; mt < 4; ++mt) {
                int rowa = wm + mt * 16 + (lane & 15);
                int kba = ((lane >> 4) * 16 + ks * 64) ^ ((rowa & 7) << 4);
                af[mt] = *(const short8*)((const char*)At + rowa * 128 + kba);
                int rowb = wn + mt * 16 + (lane & 15);
                int kbb = ((lane >> 4) * 16 + ks * 64) ^ ((rowb & 7) << 4);
                bf[mt] = *(const short8*)((const char*)Bt + rowb * 128 + kbb);
            }
#pragma unroll
            for (int mt = 0; mt < 4; ++mt)
#pragma unroll
                for (int nt = 0; nt < 4; ++nt)
                    acc[mt][nt] = MFMA(af[mt], bf[nt], acc[mt][nt]);
        }
        __syncthreads();
    }
#pragma unroll
    for (int mt = 0; mt < 4; ++mt) {
#pragma unroll
        for (int nt = 0; nt < 4; ++nt) {
            int gn = n0 + wn + nt * 16 + (lane & 15);
            float bi = bias[gn];
#pragma unroll
            for (int i = 0; i < 4; ++i) {
                int gm = m0 + wm + mt * 16 + (lane >> 4) * 4 + i;
                float v = acc[mt][nt][i] + bi;
                size_t idx = (size_t)gm * (size_t)N + gn;
                if constexpr (EPI == 0) {
                    Cb[idx] = f2bf(v);
                } else if constexpr (EPI == 1) {
                    v = 0.5f * v * (1.f + erff(v * 0.70710678118f));
                    Cb[idx] = f2bf(v);
                } else {
                    Cf[idx] = v + Xres[idx] + bf2f(Rres[idx]);
                }
            }
        }
    }
}

// ---------- LSTM scan ----------
// 64 WGs = 4 batch-groups x 16 N-slices, 512 threads (8 waves).
// Exchange: tagged u32 words (tag<<16 | bf16 h), double-buffered by step parity.
// Poll IS the data load: one L3 round trip per step. Safety: P=2 + data dependence
// (a producer's tag-u publish depends on having read all of h(u-1)).
__global__ __launch_bounds__(512, 1)
void k_scan(const u16* __restrict__ gx, const u16* __restrict__ whh,
            u16* __restrict__ rout, u32* __restrict__ h_ex) {
    const int grp = blockIdx.x >> 4, sl = blockIdx.x & 15;
    const int tid = threadIdx.x;
    const int lane = tid & 63, wv = tid >> 6;
    const int gt = wv >> 1, jb = wv & 1;
    const int cb = gt * 512 + sl * 32 + jb * 16;

    __shared__ __align__(16) u16 h_lds[16 * 512];  // swizzled 16KB
    __shared__ float g_buf[128 * 17];              // [localcol][batch]

    // register-resident weight fragments (64 VGPRs, loaded once)
    short8 wf[16];
    {
        const u16* wp = whh + (size_t)(cb + (lane & 15)) * 512 + (lane >> 4) * 8;
#pragma unroll
        for (int ks = 0; ks < 16; ++ks) wf[ks] = *(const short8*)(wp + ks * 32);
    }
    const int b_own = tid >> 5, jj = tid & 31;
    float cst = 0.f;
    u32* hex_g = h_ex + (u32)grp * 16384u;
    const int lc = gt * 32 + jb * 16 + (lane & 15);
    const int ngl = cb + (lane & 15);
    // poll ownership: 16 consecutive words -> batch pb, cols pj0..pj0+15
    const int pw0 = tid * 16;
    const int pb = tid >> 5, pj0 = (tid & 31) * 16;
    const int sw_w = (pb & 7) << 4;
    char* ldst0 = (char*)h_lds + pb * 1024 + ((pj0 * 2) ^ sw_w);
    char* ldst1 = (char*)h_lds + pb * 1024 + (((pj0 + 8) * 2) ^ sw_w);
    const u32 pub_idx = (u32)(b_own * 512 + sl * 32 + jj);

    for (int t = 0; t < 1024; ++t) {
        // gx prefetch (overlaps the poll)
        float gxv[4];
#pragma unroll
        for (int i = 0; i < 4; ++i) {
            int bg = grp * 16 + (lane >> 4) * 4 + i;
            gxv[i] = bf2f(gx[((size_t)bg * 1024 + t) * 2048 + ngl]);
        }
        // poll own 16 tagged words
        const u32* src = hex_g + (u32)(t & 1) * 8192u + pw0;
        u32 w[16];
        for (;;) {
            bool ok = true;
#pragma unroll
            for (int e = 0; e < 16; ++e)
                w[e] = __hip_atomic_load(src + e, __ATOMIC_RELAXED, __HIP_MEMORY_SCOPE_AGENT);
#pragma unroll
            for (int e = 0; e < 16; ++e) ok &= ((w[e] >> 16) == (u32)t);
            if (ok) break;
            __builtin_amdgcn_s_sleep(1);
        }
        // extract bf16, write LDS swizzled (two 16B stores)
        u16 hb16[16];
#pragma unroll
        for (int e = 0; e < 16; ++e) hb16[e] = (u16)(w[e] & 0xffffu);
        *(short8*)ldst0 = *(const short8*)(hb16);
        *(short8*)ldst1 = *(const short8*)(hb16 + 8);
        __syncthreads();
        // wave GEMM: 16 cols x K=512, 4 independent acc chains
        f32x4 a0 = {}, a1 = {}, a2 = {}, a3 = {};
        {
            const int rowa = lane & 15;
            const int kb0 = (lane >> 4) * 16;
            const int sw = (rowa & 7) << 4;
            const char* rb_ = (const char*)h_lds + rowa * 1024;
#pragma unroll
            for (int ks = 0; ks < 4; ++ks) {
                a0 = MFMA(*(const short8*)(rb_ + ((kb0 + (4 * ks + 0) * 64) ^ sw)), wf[4 * ks + 0], a0);
                a1 = MFMA(*(const short8*)(rb_ + ((kb0 + (4 * ks + 1) * 64) ^ sw)), wf[4 * ks + 1], a1);
                a2 = MFMA(*(const short8*)(rb_ + ((kb0 + (4 * ks + 2) * 64) ^ sw)), wf[4 * ks + 2], a2);
                a3 = MFMA(*(const short8*)(rb_ + ((kb0 + (4 * ks + 3) * 64) ^ sw)), wf[4 * ks + 3], a3);
            }
        }
        f32x4 acc = (a0 + a1) + (a2 + a3);
#pragma unroll
        for (int i = 0; i < 4; ++i)
            g_buf[lc * 17 + ((lane >> 4) * 4 + i)] = acc[i] + gxv[i];
        __syncthreads();
        // gates + state update + publish
        {
            float iv = g_buf[jj * 17 + b_own];
            float fv = g_buf[(jj + 32) * 17 + b_own];
            float gv = g_buf[(jj + 64) * 17 + b_own];
            float ov = g_buf[(jj + 96) * 17 + b_own];
            cst = sigm(fv) * cst + sigm(iv) * tanh_f(gv);
            float h = sigm(ov) * tanh_f(cst);
            u16 hb = f2bf(h);
            rout[((size_t)(grp * 16 + b_own) * 1024 + t) * 512 + sl * 32 + jj] = hb;
            __hip_atomic_store(hex_g + (u32)((t + 1) & 1) * 8192u + pub_idx,
                               ((u32)(t + 1) << 16) | (u32)hb,
                               __ATOMIC_RELAXED, __HIP_MEMORY_SCOPE_AGENT);
        }
    }
}

// ---------- launch ----------
extern "C" void kernel_launch(void* const* d_in, const int* in_sizes, int n_in,
                              void* d_out, int out_size, void* d_ws, size_t ws_size,
                              hipStream_t stream) {
    const float* x     = (const float*)d_in[0];
    const float* pre_g = (const float*)d_in[1];
    const float* pre_b = (const float*)d_in[2];
    const float* w_ih  = (const float*)d_in[3];
    const float* w_hh  = (const float*)d_in[4];
    const float* b_ih  = (const float*)d_in[5];
    const float* b_hh  = (const float*)d_in[6];
    const float* post_g= (const float*)d_in[7];
    const float* post_b= (const float*)d_in[8];
    const float* w1    = (const float*)d_in[9];
    const float* b1    = (const float*)d_in[10];
    const float* w2    = (const float*)d_in[11];
    const float* b2    = (const float*)d_in[12];
    float* out = (float*)d_out;

    char* p = (char*)d_ws;
    auto carve = [&](size_t bytes) { void* r = (void*)p; p += (bytes + 255) & ~(size_t)255; return r; };
    u16* xln   = (u16*)carve(64ull * 1024 * 512 * 2);    // 64 MiB; reused as ln1 after GEMM1
    u16* gxb   = (u16*)carve(64ull * 1024 * 2048 * 2);   // 256 MiB; reused as h1 after scan
    u16* rb    = (u16*)carve(64ull * 1024 * 512 * 2);    // 64 MiB
    u16* wihb  = (u16*)carve(2048ull * 512 * 2);
    u16* whhb  = (u16*)carve(2048ull * 512 * 2);
    u16* w1t   = (u16*)carve(1024ull * 512 * 2);
    u16* w2t   = (u16*)carve(512ull * 1024 * 2);
    float* biasc = (float*)carve(2048ull * 4);
    u32* h_ex  = (u32*)carve(65536ull * 4);              // 4 groups x 2 parities x 8192 tagged u32
    u16* ln1 = xln;   // alias: xln dead after GEMM1
    u16* h1  = gxb;   // alias: gx dead after scan

    k_prep<<<3072, 256, 0, stream>>>(w_ih, w_hh, b_ih, b_hh, w1, w2, wihb, whhb, w1t, w2t, biasc);
    k_init<<<256, 256, 0, stream>>>(h_ex);
    k_pre_ln<<<16384, 256, 0, stream>>>(x, pre_g, pre_b, xln);
    k_gemm<512, 0><<<dim3(16, 512), 256, 0, stream>>>(xln, wihb, biasc, gxb, nullptr, nullptr, nullptr, 2048);
    k_scan<<<64, 512, 0, stream>>>(gxb, whhb, rb, h_ex);
    k_res_ln<<<16384, 256, 0, stream>>>(x, rb, post_g, post_b, ln1);
    k_gemm<512, 1><<<dim3(8, 512), 256, 0, stream>>>(ln1, w1t, b1, h1, nullptr, nullptr, nullptr, 1024);
    k_gemm<1024, 2><<<dim3(4, 512), 256, 0, stream>>>(h1, w2t, b2, nullptr, out, x, rb, 512);
}

// Round 4
// 7023.026 us; speedup vs baseline: 1.0006x; 1.0006x over previous
//
#include <hip/hip_runtime.h>

typedef unsigned short u16;
typedef unsigned int   u32;
typedef unsigned long long u64;
typedef __attribute__((ext_vector_type(4))) float f32x4;
typedef __attribute__((ext_vector_type(8))) short short8;
typedef __attribute__((ext_vector_type(8))) __bf16 bf16x8v;

// ---------- bf16 helpers (manual, RNE) ----------
__device__ __forceinline__ float bf2f(u16 v) { return __uint_as_float(((u32)v) << 16); }
__device__ __forceinline__ u16 f2bf(float f) {
    u32 u = __float_as_uint(f);
    u32 r = (u + 0x7fffu + ((u >> 16) & 1u)) >> 16;
    return (u16)r;
}
__device__ __forceinline__ float sigm(float x) { return 1.f / (1.f + __expf(-x)); }
__device__ __forceinline__ float tanh_f(float x) { return 1.f - 2.f / (__expf(2.f * x) + 1.f); }

// ---------- MFMA wrapper: works whether builtin wants short8 or v8bf16 ----------
template <class A>
__device__ __forceinline__ auto try_mfma(A a, A b, f32x4 c, int)
    -> decltype(__builtin_amdgcn_mfma_f32_16x16x32_bf16(a, b, c, 0, 0, 0)) {
    return __builtin_amdgcn_mfma_f32_16x16x32_bf16(a, b, c, 0, 0, 0);
}
template <class A>
__device__ __forceinline__ f32x4 try_mfma(A a, A b, f32x4 c, long) {
    return __builtin_amdgcn_mfma_f32_16x16x32_bf16(
        __builtin_bit_cast(bf16x8v, a), __builtin_bit_cast(bf16x8v, b), c, 0, 0, 0);
}
__device__ __forceinline__ f32x4 MFMA(short8 a, short8 b, f32x4 c) { return try_mfma(a, b, c, 0); }

// B=64, S=1024, H=512 fixed.

// ---------- prep: bf16 weight copies / transposes / combined bias ----------
__global__ void k_prep(const float* __restrict__ w_ih, const float* __restrict__ w_hh,
                       const float* __restrict__ b_ih, const float* __restrict__ b_hh,
                       const float* __restrict__ w1, const float* __restrict__ w2,
                       u16* __restrict__ wihb, u16* __restrict__ whhb,
                       u16* __restrict__ w1t, u16* __restrict__ w2t, float* __restrict__ biasc) {
    for (u32 i = blockIdx.x * blockDim.x + threadIdx.x; i < 3147776u; i += gridDim.x * blockDim.x) {
        if (i < 1048576u) { wihb[i] = f2bf(w_ih[i]); }
        else if (i < 2097152u) { u32 j = i - 1048576u; whhb[j] = f2bf(w_hh[j]); }
        else if (i < 2621440u) { u32 j = i - 2097152u; u32 n = j >> 9,  k = j & 511u;  w1t[j] = f2bf(w1[k * 1024u + n]); }
        else if (i < 3145728u) { u32 j = i - 2621440u; u32 n = j >> 10, k = j & 1023u; w2t[j] = f2bf(w2[k * 512u + n]); }
        else { u32 j = i - 3145728u; biasc[j] = b_ih[j] + b_hh[j]; }
    }
}

// ---------- init: zero tagged exchange buffer (tag0 == h(0)=0) ----------
__global__ void k_init(u32* __restrict__ h_ex) {
    u32 i = blockIdx.x * blockDim.x + threadIdx.x;
    if (i < 65536u) h_ex[i] = 0u;
}

// ---------- LayerNorm: one wave per row of 512 ----------
__global__ __launch_bounds__(256) void k_pre_ln(const float* __restrict__ x,
                                                const float* __restrict__ g, const float* __restrict__ b,
                                                u16* __restrict__ out) {
    const int row = blockIdx.x * 4 + (threadIdx.x >> 6);
    const int lane = threadIdx.x & 63;
    const float* xr = x + (size_t)row * 512 + lane * 8;
    float v[8];
    *(float4*)(v)     = *(const float4*)(xr);
    *(float4*)(v + 4) = *(const float4*)(xr + 4);
    float s = 0.f, q = 0.f;
#pragma unroll
    for (int e = 0; e < 8; ++e) { s += v[e]; q += v[e] * v[e]; }
#pragma unroll
    for (int o = 32; o; o >>= 1) { s += __shfl_xor(s, o); q += __shfl_xor(q, o); }
    float mu = s * (1.f / 512.f);
    float rs = rsqrtf(q * (1.f / 512.f) - mu * mu + 1e-5f);
    short8 ov;
#pragma unroll
    for (int e = 0; e < 8; ++e) {
        int cidx = lane * 8 + e;
        ov[e] = (short)f2bf((v[e] - mu) * rs * g[cidx] + b[cidx]);
    }
    *(short8*)(out + (size_t)row * 512 + lane * 8) = ov;
}

__global__ __launch_bounds__(256) void k_res_ln(const float* __restrict__ x, const u16* __restrict__ r,
                                                const float* __restrict__ g, const float* __restrict__ b,
                                                u16* __restrict__ out) {
    const int row = blockIdx.x * 4 + (threadIdx.x >> 6);
    const int lane = threadIdx.x & 63;
    const float* xr = x + (size_t)row * 512 + lane * 8;
    short8 rv = *(const short8*)(r + (size_t)row * 512 + lane * 8);
    float v[8];
    *(float4*)(v)     = *(const float4*)(xr);
    *(float4*)(v + 4) = *(const float4*)(xr + 4);
#pragma unroll
    for (int e = 0; e < 8; ++e) v[e] += bf2f((u16)rv[e]);
    float s = 0.f, q = 0.f;
#pragma unroll
    for (int e = 0; e < 8; ++e) { s += v[e]; q += v[e] * v[e]; }
#pragma unroll
    for (int o = 32; o; o >>= 1) { s += __shfl_xor(s, o); q += __shfl_xor(q, o); }
    float mu = s * (1.f / 512.f);
    float rs = rsqrtf(q * (1.f / 512.f) - mu * mu + 1e-5f);
    short8 ov;
#pragma unroll
    for (int e = 0; e < 8; ++e) {
        int cidx = lane * 8 + e;
        ov[e] = (short)f2bf((v[e] - mu) * rs * g[cidx] + b[cidx]);
    }
    *(short8*)(out + (size_t)row * 512 + lane * 8) = ov;
}

// ---------- GEMM (B^T layout): C[m,n] = sum_k A[m,k]*B[n,k] (+bias, epilogues) ----------
template <int KD, int EPI>
__global__ __launch_bounds__(256, 2)
void k_gemm(const u16* __restrict__ A, const u16* __restrict__ B,
            const float* __restrict__ bias, u16* __restrict__ Cb, float* __restrict__ Cf,
            const float* __restrict__ Xres, const u16* __restrict__ Rres, int N) {
    __shared__ __align__(16) u16 At[128 * 64];
    __shared__ __align__(16) u16 Bt[128 * 64];
    const int tid = threadIdx.x;
    const int lane = tid & 63, wv = tid >> 6;
    const int m0 = blockIdx.y << 7, n0 = blockIdx.x << 7;
    const int wm = (wv >> 1) << 6, wn = (wv & 1) << 6;
    f32x4 acc[4][4] = {};
    const int r_st = tid >> 3, kb_st = tid & 7;

    for (int k0 = 0; k0 < KD; k0 += 64) {
#pragma unroll
        for (int rnd = 0; rnd < 4; ++rnd) {
            int rr = r_st + rnd * 32;
            short8 va = *(const short8*)(A + (size_t)(m0 + rr) * KD + (k0 + kb_st * 8));
            short8 vb = *(const short8*)(B + (size_t)(n0 + rr) * KD + (k0 + kb_st * 8));
            int byt = rr * 128 + ((kb_st * 16) ^ ((rr & 7) << 4));
            *(short8*)((char*)At + byt) = va;
            *(short8*)((char*)Bt + byt) = vb;
        }
        __syncthreads();
#pragma unroll
        for (int ks = 0; ks < 2; ++ks) {
            short8 af[4], bf[4];
#pragma unroll
            for (int mt = 0; mt < 4; ++mt) {
                int rowa = wm + mt * 16 + (lane & 15);
                int kba = ((lane >> 4) * 16 + ks * 64) ^ ((rowa & 7) << 4);
                af[mt] = *(const short8*)((const char*)At + rowa * 128 + kba);
                int rowb = wn + mt * 16 + (lane & 15);
                int kbb = ((lane >> 4) * 16 + ks * 64) ^ ((rowb & 7) << 4);
                bf[mt] = *(const short8*)((const char*)Bt + rowb * 128 + kbb);
            }
#pragma unroll
            for (int mt = 0; mt < 4; ++mt)
#pragma unroll
                for (int nt = 0; nt < 4; ++nt)
                    acc[mt][nt] = MFMA(af[mt], bf[nt], acc[mt][nt]);
        }
        __syncthreads();
    }
#pragma unroll
    for (int mt = 0; mt < 4; ++mt) {
#pragma unroll
        for (int nt = 0; nt < 4; ++nt) {
            int gn = n0 + wn + nt * 16 + (lane & 15);
            float bi = bias[gn];
#pragma unroll
            for (int i = 0; i < 4; ++i) {
                int gm = m0 + wm + mt * 16 + (lane >> 4) * 4 + i;
                float v = acc[mt][nt][i] + bi;
                size_t idx = (size_t)gm * (size_t)N + gn;
                if constexpr (EPI == 0) {
                    Cb[idx] = f2bf(v);
                } else if constexpr (EPI == 1) {
                    v = 0.5f * v * (1.f + erff(v * 0.70710678118f));
                    Cb[idx] = f2bf(v);
                } else {
                    Cf[idx] = v + Xres[idx] + bf2f(Rres[idx]);
                }
            }
        }
    }
}

// ---------- LSTM scan ----------
// 64 WGs = 4 batch-groups x 16 N-slices, 512 threads (8 waves).
// Exchange: tagged u32 words (tag<<16 | bf16 h), double-buffered by step parity.
// Poll IS the data load: one L3 round trip per step. Safety: P=2 + data dependence
// (a producer's tag-u publish depends on having read all of h(u-1)).
__global__ __launch_bounds__(512, 1)
void k_scan(const u16* __restrict__ gx, const u16* __restrict__ whh,
            u16* __restrict__ rout, u32* __restrict__ h_ex) {
    const int grp = blockIdx.x >> 4, sl = blockIdx.x & 15;
    const int tid = threadIdx.x;
    const int lane = tid & 63, wv = tid >> 6;
    const int gt = wv >> 1, jb = wv & 1;
    const int cb = gt * 512 + sl * 32 + jb * 16;

    __shared__ __align__(16) u16 h_lds[16 * 512];  // swizzled 16KB
    __shared__ float g_buf[128 * 17];              // [localcol][batch]

    // register-resident weight fragments (64 VGPRs, loaded once)
    short8 wf[16];
    {
        const u16* wp = whh + (size_t)(cb + (lane & 15)) * 512 + (lane >> 4) * 8;
#pragma unroll
        for (int ks = 0; ks < 16; ++ks) wf[ks] = *(const short8*)(wp + ks * 32);
    }
    const int b_own = tid >> 5, jj = tid & 31;
    float cst = 0.f;
    u32* hex_g = h_ex + (u32)grp * 16384u;
    const int lc = gt * 32 + jb * 16 + (lane & 15);
    const int ngl = cb + (lane & 15);
    // poll ownership: 16 consecutive words -> batch pb, cols pj0..pj0+15
    const int pw0 = tid * 16;
    const int pb = tid >> 5, pj0 = (tid & 31) * 16;
    const int sw_w = (pb & 7) << 4;
    char* ldst0 = (char*)h_lds + pb * 1024 + ((pj0 * 2) ^ sw_w);
    char* ldst1 = (char*)h_lds + pb * 1024 + (((pj0 + 8) * 2) ^ sw_w);
    const u32 pub_idx = (u32)(b_own * 512 + sl * 32 + jj);

    for (int t = 0; t < 1024; ++t) {
        // gx prefetch (overlaps the poll)
        float gxv[4];
#pragma unroll
        for (int i = 0; i < 4; ++i) {
            int bg = grp * 16 + (lane >> 4) * 4 + i;
            gxv[i] = bf2f(gx[((size_t)bg * 1024 + t) * 2048 + ngl]);
        }
        // poll own 16 tagged words
        const u32* src = hex_g + (u32)(t & 1) * 8192u + pw0;
        u32 w[16];
        for (;;) {
            bool ok = true;
#pragma unroll
            for (int e = 0; e < 16; ++e)
                w[e] = __hip_atomic_load(src + e, __ATOMIC_RELAXED, __HIP_MEMORY_SCOPE_AGENT);
#pragma unroll
            for (int e = 0; e < 16; ++e) ok &= ((w[e] >> 16) == (u32)t);
            if (ok) break;
            __builtin_amdgcn_s_sleep(1);
        }
        // extract bf16, write LDS swizzled (two 16B stores)
        u16 hb16[16];
#pragma unroll
        for (int e = 0; e < 16; ++e) hb16[e] = (u16)(w[e] & 0xffffu);
        *(short8*)ldst0 = *(const short8*)(hb16);
        *(short8*)ldst1 = *(const short8*)(hb16 + 8);
        __syncthreads();
        // wave GEMM: 16 cols x K=512, 4 independent acc chains
        f32x4 a0 = {}, a1 = {}, a2 = {}, a3 = {};
        {
            const int rowa = lane & 15;
            const int kb0 = (lane >> 4) * 16;
            const int sw = (rowa & 7) << 4;
            const char* rb_ = (const char*)h_lds + rowa * 1024;
#pragma unroll
            for (int ks = 0; ks < 4; ++ks) {
                a0 = MFMA(*(const short8*)(rb_ + ((kb0 + (4 * ks + 0) * 64) ^ sw)), wf[4 * ks + 0], a0);
                a1 = MFMA(*(const short8*)(rb_ + ((kb0 + (4 * ks + 1) * 64) ^ sw)), wf[4 * ks + 1], a1);
                a2 = MFMA(*(const short8*)(rb_ + ((kb0 + (4 * ks + 2) * 64) ^ sw)), wf[4 * ks + 2], a2);
                a3 = MFMA(*(const short8*)(rb_ + ((kb0 + (4 * ks + 3) * 64) ^ sw)), wf[4 * ks + 3], a3);
            }
        }
        f32x4 acc = (a0 + a1) + (a2 + a3);
#pragma unroll
        for (int i = 0; i < 4; ++i)
            g_buf[lc * 17 + ((lane >> 4) * 4 + i)] = acc[i] + gxv[i];
        __syncthreads();
        // gates + state update + publish
        {
            float iv = g_buf[jj * 17 + b_own];
            float fv = g_buf[(jj + 32) * 17 + b_own];
            float gv = g_buf[(jj + 64) * 17 + b_own];
            float ov = g_buf[(jj + 96) * 17 + b_own];
            cst = sigm(fv) * cst + sigm(iv) * tanh_f(gv);
            float h = sigm(ov) * tanh_f(cst);
            u16 hb = f2bf(h);
            rout[((size_t)(grp * 16 + b_own) * 1024 + t) * 512 + sl * 32 + jj] = hb;
            __hip_atomic_store(hex_g + (u32)((t + 1) & 1) * 8192u + pub_idx,
                               ((u32)(t + 1) << 16) | (u32)hb,
                               __ATOMIC_RELAXED, __HIP_MEMORY_SCOPE_AGENT);
        }
    }
}

// ---------- launch ----------
extern "C" void kernel_launch(void* const* d_in, const int* in_sizes, int n_in,
                              void* d_out, int out_size, void* d_ws, size_t ws_size,
                              hipStream_t stream) {
    const float* x     = (const float*)d_in[0];
    const float* pre_g = (const float*)d_in[1];
    const float* pre_b = (const float*)d_in[2];
    const float* w_ih  = (const float*)d_in[3];
    const float* w_hh  = (const float*)d_in[4];
    const float* b_ih  = (const float*)d_in[5];
    const float* b_hh  = (const float*)d_in[6];
    const float* post_g= (const float*)d_in[7];
    const float* post_b= (const float*)d_in[8];
    const float* w1    = (const float*)d_in[9];
    const float* b1    = (const float*)d_in[10];
    const float* w2    = (const float*)d_in[11];
    const float* b2    = (const float*)d_in[12];
    float* out = (float*)d_out;

    char* p = (char*)d_ws;
    auto carve = [&](size_t bytes) { void* r = (void*)p; p += (bytes + 255) & ~(size_t)255; return r; };
    u16* xln   = (u16*)carve(64ull * 1024 * 512 * 2);    // 64 MiB; reused as ln1 after GEMM1
    u16* gxb   = (u16*)carve(64ull * 1024 * 2048 * 2);   // 256 MiB; reused as h1 after scan
    u16* rb    = (u16*)carve(64ull * 1024 * 512 * 2);    // 64 MiB
    u16* wihb  = (u16*)carve(2048ull * 512 * 2);
    u16* whhb  = (u16*)carve(2048ull * 512 * 2);
    u16* w1t   = (u16*)carve(1024ull * 512 * 2);
    u16* w2t   = (u16*)carve(512ull * 1024 * 2);
    float* biasc = (float*)carve(2048ull * 4);
    u32* h_ex  = (u32*)carve(65536ull * 4);              // 4 groups x 2 parities x 8192 tagged u32
    u16* ln1 = xln;   // alias: xln dead after GEMM1
    u16* h1  = gxb;   // alias: gx dead after scan

    k_prep<<<3072, 256, 0, stream>>>(w_ih, w_hh, b_ih, b_hh, w1, w2, wihb, whhb, w1t, w2t, biasc);
    k_init<<<256, 256, 0, stream>>>(h_ex);
    k_pre_ln<<<16384, 256, 0, stream>>>(x, pre_g, pre_b, xln);
    k_gemm<512, 0><<<dim3(16, 512), 256, 0, stream>>>(xln, wihb, biasc, gxb, nullptr, nullptr, nullptr, 2048);
    k_scan<<<64, 512, 0, stream>>>(gxb, whhb, rb, h_ex);
    k_res_ln<<<16384, 256, 0, stream>>>(x, rb, post_g, post_b, ln1);
    k_gemm<512, 1><<<dim3(8, 512), 256, 0, stream>>>(ln1, w1t, b1, h1, nullptr, nullptr, nullptr, 1024);
    k_gemm<1024, 2><<<dim3(4, 512), 256, 0, stream>>>(h1, w2t, b2, nullptr, out, x, rb, 512);
}

// Round 5
// 3657.971 us; speedup vs baseline: 1.9211x; 1.9199x over previous
//
#include <hip/hip_runtime.h>

typedef unsigned short u16;
typedef unsigned int   u32;
typedef unsigned long long u64;
typedef __attribute__((ext_vector_type(4))) float f32x4;
typedef __attribute__((ext_vector_type(8))) short short8;
typedef __attribute__((ext_vector_type(8))) __bf16 bf16x8v;
typedef __attribute__((ext_vector_type(4))) u32 u32x4;

// ---------- bf16 helpers (manual, RNE) ----------
__device__ __forceinline__ float bf2f(u16 v) { return __uint_as_float(((u32)v) << 16); }
__device__ __forceinline__ u16 f2bf(float f) {
    u32 u = __float_as_uint(f);
    u32 r = (u + 0x7fffu + ((u >> 16) & 1u)) >> 16;
    return (u16)r;
}
__device__ __forceinline__ float sigm(float x) { return 1.f / (1.f + __expf(-x)); }
__device__ __forceinline__ float tanh_f(float x) { return 1.f - 2.f / (__expf(2.f * x) + 1.f); }

// ---------- MFMA wrapper: works whether builtin wants short8 or v8bf16 ----------
template <class A>
__device__ __forceinline__ auto try_mfma(A a, A b, f32x4 c, int)
    -> decltype(__builtin_amdgcn_mfma_f32_16x16x32_bf16(a, b, c, 0, 0, 0)) {
    return __builtin_amdgcn_mfma_f32_16x16x32_bf16(a, b, c, 0, 0, 0);
}
template <class A>
__device__ __forceinline__ f32x4 try_mfma(A a, A b, f32x4 c, long) {
    return __builtin_amdgcn_mfma_f32_16x16x32_bf16(
        __builtin_bit_cast(bf16x8v, a), __builtin_bit_cast(bf16x8v, b), c, 0, 0, 0);
}
__device__ __forceinline__ f32x4 MFMA(short8 a, short8 b, f32x4 c) { return try_mfma(a, b, c, 0); }

// ---------- coherent (cache-bypassing) wide load / store via sc0 sc1 ----------
__device__ __forceinline__ void cload4(const u32* p0, const u32* p1, const u32* p2, const u32* p3,
                                       u32x4& a, u32x4& b, u32x4& c, u32x4& d) {
    asm volatile("global_load_dwordx4 %0, %4, off sc0 sc1\n\t"
                 "global_load_dwordx4 %1, %5, off sc0 sc1\n\t"
                 "global_load_dwordx4 %2, %6, off sc0 sc1\n\t"
                 "global_load_dwordx4 %3, %7, off sc0 sc1\n\t"
                 "s_waitcnt vmcnt(0)"
                 : "=&v"(a), "=&v"(b), "=&v"(c), "=&v"(d)
                 : "v"(p0), "v"(p1), "v"(p2), "v"(p3)
                 : "memory");
}
__device__ __forceinline__ void cstore1(u32* p, u32 v) {
    asm volatile("global_store_dword %0, %1, off sc0 sc1" :: "v"(p), "v"(v) : "memory");
}

// B=64, S=1024, H=512 fixed.

// ---------- prep: bf16 weight copies / transposes / combined bias ----------
__global__ void k_prep(const float* __restrict__ w_ih, const float* __restrict__ w_hh,
                       const float* __restrict__ b_ih, const float* __restrict__ b_hh,
                       const float* __restrict__ w1, const float* __restrict__ w2,
                       u16* __restrict__ wihb, u16* __restrict__ whhb,
                       u16* __restrict__ w1t, u16* __restrict__ w2t, float* __restrict__ biasc) {
    for (u32 i = blockIdx.x * blockDim.x + threadIdx.x; i < 3147776u; i += gridDim.x * blockDim.x) {
        if (i < 1048576u) { wihb[i] = f2bf(w_ih[i]); }
        else if (i < 2097152u) { u32 j = i - 1048576u; whhb[j] = f2bf(w_hh[j]); }
        else if (i < 2621440u) { u32 j = i - 2097152u; u32 n = j >> 9,  k = j & 511u;  w1t[j] = f2bf(w1[k * 1024u + n]); }
        else if (i < 3145728u) { u32 j = i - 2621440u; u32 n = j >> 10, k = j & 1023u; w2t[j] = f2bf(w2[k * 512u + n]); }
        else { u32 j = i - 3145728u; biasc[j] = b_ih[j] + b_hh[j]; }
    }
}

// ---------- init: zero tagged exchange buffer (tag0 == h(0)=0) ----------
__global__ void k_init(u32* __restrict__ h_ex) {
    u32 i = blockIdx.x * blockDim.x + threadIdx.x;
    if (i < 65536u) h_ex[i] = 0u;
}

// ---------- LayerNorm: one wave per row of 512 ----------
__global__ __launch_bounds__(256) void k_pre_ln(const float* __restrict__ x,
                                                const float* __restrict__ g, const float* __restrict__ b,
                                                u16* __restrict__ out) {
    const int row = blockIdx.x * 4 + (threadIdx.x >> 6);
    const int lane = threadIdx.x & 63;
    const float* xr = x + (size_t)row * 512 + lane * 8;
    float v[8];
    *(float4*)(v)     = *(const float4*)(xr);
    *(float4*)(v + 4) = *(const float4*)(xr + 4);
    float s = 0.f, q = 0.f;
#pragma unroll
    for (int e = 0; e < 8; ++e) { s += v[e]; q += v[e] * v[e]; }
#pragma unroll
    for (int o = 32; o; o >>= 1) { s += __shfl_xor(s, o); q += __shfl_xor(q, o); }
    float mu = s * (1.f / 512.f);
    float rs = rsqrtf(q * (1.f / 512.f) - mu * mu + 1e-5f);
    short8 ov;
#pragma unroll
    for (int e = 0; e < 8; ++e) {
        int cidx = lane * 8 + e;
        ov[e] = (short)f2bf((v[e] - mu) * rs * g[cidx] + b[cidx]);
    }
    *(short8*)(out + (size_t)row * 512 + lane * 8) = ov;
}

__global__ __launch_bounds__(256) void k_res_ln(const float* __restrict__ x, const u16* __restrict__ r,
                                                const float* __restrict__ g, const float* __restrict__ b,
                                                u16* __restrict__ out) {
    const int row = blockIdx.x * 4 + (threadIdx.x >> 6);
    const int lane = threadIdx.x & 63;
    const float* xr = x + (size_t)row * 512 + lane * 8;
    short8 rv = *(const short8*)(r + (size_t)row * 512 + lane * 8);
    float v[8];
    *(float4*)(v)     = *(const float4*)(xr);
    *(float4*)(v + 4) = *(const float4*)(xr + 4);
#pragma unroll
    for (int e = 0; e < 8; ++e) v[e] += bf2f((u16)rv[e]);
    float s = 0.f, q = 0.f;
#pragma unroll
    for (int e = 0; e < 8; ++e) { s += v[e]; q += v[e] * v[e]; }
#pragma unroll
    for (int o = 32; o; o >>= 1) { s += __shfl_xor(s, o); q += __shfl_xor(q, o); }
    float mu = s * (1.f / 512.f);
    float rs = rsqrtf(q * (1.f / 512.f) - mu * mu + 1e-5f);
    short8 ov;
#pragma unroll
    for (int e = 0; e < 8; ++e) {
        int cidx = lane * 8 + e;
        ov[e] = (short)f2bf((v[e] - mu) * rs * g[cidx] + b[cidx]);
    }
    *(short8*)(out + (size_t)row * 512 + lane * 8) = ov;
}

// ---------- GEMM (B^T layout): C[m,n] = sum_k A[m,k]*B[n,k] (+bias, epilogues) ----------
template <int KD, int EPI>
__global__ __launch_bounds__(256, 2)
void k_gemm(const u16* __restrict__ A, const u16* __restrict__ B,
            const float* __restrict__ bias, u16* __restrict__ Cb, float* __restrict__ Cf,
            const float* __restrict__ Xres, const u16* __restrict__ Rres, int N) {
    __shared__ __align__(16) u16 At[128 * 64];
    __shared__ __align__(16) u16 Bt[128 * 64];
    const int tid = threadIdx.x;
    const int lane = tid & 63, wv = tid >> 6;
    const int m0 = blockIdx.y << 7, n0 = blockIdx.x << 7;
    const int wm = (wv >> 1) << 6, wn = (wv & 1) << 6;
    f32x4 acc[4][4] = {};
    const int r_st = tid >> 3, kb_st = tid & 7;

    for (int k0 = 0; k0 < KD; k0 += 64) {
#pragma unroll
        for (int rnd = 0; rnd < 4; ++rnd) {
            int rr = r_st + rnd * 32;
            short8 va = *(const short8*)(A + (size_t)(m0 + rr) * KD + (k0 + kb_st * 8));
            short8 vb = *(const short8*)(B + (size_t)(n0 + rr) * KD + (k0 + kb_st * 8));
            int byt = rr * 128 + ((kb_st * 16) ^ ((rr & 7) << 4));
            *(short8*)((char*)At + byt) = va;
            *(short8*)((char*)Bt + byt) = vb;
        }
        __syncthreads();
#pragma unroll
        for (int ks = 0; ks < 2; ++ks) {
            short8 af[4], bf[4];
#pragma unroll
            for (int mt = 0; mt < 4; ++mt) {
                int rowa = wm + mt * 16 + (lane & 15);
                int kba = ((lane >> 4) * 16 + ks * 64) ^ ((rowa & 7) << 4);
                af[mt] = *(const short8*)((const char*)At + rowa * 128 + kba);
                int rowb = wn + mt * 16 + (lane & 15);
                int kbb = ((lane >> 4) * 16 + ks * 64) ^ ((rowb & 7) << 4);
                bf[mt] = *(const short8*)((const char*)Bt + rowb * 128 + kbb);
            }
#pragma unroll
            for (int mt = 0; mt < 4; ++mt)
#pragma unroll
                for (int nt = 0; nt < 4; ++nt)
                    acc[mt][nt] = MFMA(af[mt], bf[nt], acc[mt][nt]);
        }
        __syncthreads();
    }
#pragma unroll
    for (int mt = 0; mt < 4; ++mt) {
#pragma unroll
        for (int nt = 0; nt < 4; ++nt) {
            int gn = n0 + wn + nt * 16 + (lane & 15);
            float bi = bias[gn];
#pragma unroll
            for (int i = 0; i < 4; ++i) {
                int gm = m0 + wm + mt * 16 + (lane >> 4) * 4 + i;
                float v = acc[mt][nt][i] + bi;
                size_t idx = (size_t)gm * (size_t)N + gn;
                if constexpr (EPI == 0) {
                    Cb[idx] = f2bf(v);
                } else if constexpr (EPI == 1) {
                    v = 0.5f * v * (1.f + erff(v * 0.70710678118f));
                    Cb[idx] = f2bf(v);
                } else {
                    Cf[idx] = v + Xres[idx] + bf2f(Rres[idx]);
                }
            }
        }
    }
}

// ---------- LSTM scan ----------
// 64 WGs = 4 batch-groups x 16 N-slices, 512 threads (8 waves).
// Exchange: tagged u32 words (tag<<16 | bf16 h), double-buffered by step parity.
// Poll IS the data load (one L3 round trip), now fully coalesced via coherent
// dwordx4 loads (sc0 sc1). Safety: P=2 parity slots + data dependence (a
// producer's tag-u publish is fenced, via LDS+barriers, after all its reads of
// step u-1; observing tag u from all slices proves the overwritten slot was
// consumed by everyone).
__global__ __launch_bounds__(512, 1)
void k_scan(const u16* __restrict__ gx, const u16* __restrict__ whh,
            u16* __restrict__ rout, u32* __restrict__ h_ex) {
    const int grp = blockIdx.x >> 4, sl = blockIdx.x & 15;
    const int tid = threadIdx.x;
    const int lane = tid & 63, wv = tid >> 6;
    const int gt = wv >> 1, jb = wv & 1;
    const int cb = gt * 512 + sl * 32 + jb * 16;

    __shared__ __align__(16) u16 h_lds[16 * 512];  // swizzled 16KB
    __shared__ float g_buf[128 * 17];              // [localcol][batch]

    // register-resident weight fragments (64 regs, loaded once; lives in AGPRs)
    short8 wf[16];
    {
        const u16* wp = whh + (size_t)(cb + (lane & 15)) * 512 + (lane >> 4) * 8;
#pragma unroll
        for (int ks = 0; ks < 16; ++ks) wf[ks] = *(const short8*)(wp + ks * 32);
    }
    const int b_own = tid >> 5, jj = tid & 31;
    float cst = 0.f;
    u32* hex_g = h_ex + (u32)grp * 16384u;
    const int lc = gt * 32 + jb * 16 + (lane & 15);
    const int ngl = cb + (lane & 15);
    const u32 pub_idx = (u32)(b_own * 512 + sl * 32 + jj);

    // poll->LDS mapping: load q covers words q*2048 + tid*4 + e
    //   -> b = q*4 + (tid>>7), j = (tid&127)*4 + e
    const int jbyte = (tid & 127) * 8;  // j0 * 2 bytes
    char* ldst[4];
#pragma unroll
    for (int q = 0; q < 4; ++q) {
        int bq = q * 4 + (tid >> 7);
        ldst[q] = (char*)h_lds + bq * 1024 + (jbyte ^ ((bq & 7) << 4));
    }

    for (int t = 0; t < 1024; ++t) {
        // gx prefetch (overlaps the poll)
        float gxv[4];
#pragma unroll
        for (int i = 0; i < 4; ++i) {
            int bg = grp * 16 + (lane >> 4) * 4 + i;
            gxv[i] = bf2f(gx[((size_t)bg * 1024 + t) * 2048 + ngl]);
        }
        // coalesced tagged poll: 4 coherent dwordx4 (each wave-load = 4KB contiguous)
        const u32* bse = hex_g + (u32)(t & 1) * 8192u + tid * 4;
        u32x4 qa, qb, qc, qd;
        for (;;) {
            cload4(bse, bse + 2048, bse + 4096, bse + 6144, qa, qb, qc, qd);
            u32 bad = 0;
#pragma unroll
            for (int e = 0; e < 4; ++e) {
                bad |= (qa[e] >> 16) ^ (u32)t;
                bad |= (qb[e] >> 16) ^ (u32)t;
                bad |= (qc[e] >> 16) ^ (u32)t;
                bad |= (qd[e] >> 16) ^ (u32)t;
            }
            if (!bad) break;
            __builtin_amdgcn_s_sleep(1);
        }
        // extract bf16 payloads -> conflict-free ds_write_b64 (8B x lane stride)
        {
            u64 p0 = (u64)(qa[0] & 0xffffu) | ((u64)(qa[1] & 0xffffu) << 16) |
                     ((u64)(qa[2] & 0xffffu) << 32) | ((u64)(qa[3] & 0xffffu) << 48);
            u64 p1 = (u64)(qb[0] & 0xffffu) | ((u64)(qb[1] & 0xffffu) << 16) |
                     ((u64)(qb[2] & 0xffffu) << 32) | ((u64)(qb[3] & 0xffffu) << 48);
            u64 p2 = (u64)(qc[0] & 0xffffu) | ((u64)(qc[1] & 0xffffu) << 16) |
                     ((u64)(qc[2] & 0xffffu) << 32) | ((u64)(qc[3] & 0xffffu) << 48);
            u64 p3 = (u64)(qd[0] & 0xffffu) | ((u64)(qd[1] & 0xffffu) << 16) |
                     ((u64)(qd[2] & 0xffffu) << 32) | ((u64)(qd[3] & 0xffffu) << 48);
            *(u64*)ldst[0] = p0;
            *(u64*)ldst[1] = p1;
            *(u64*)ldst[2] = p2;
            *(u64*)ldst[3] = p3;
        }
        __syncthreads();
        // wave GEMM: 16 cols x K=512, 4 independent acc chains
        f32x4 a0 = {}, a1 = {}, a2 = {}, a3 = {};
        {
            const int rowa = lane & 15;
            const int kb0 = (lane >> 4) * 16;
            const int sw = (rowa & 7) << 4;
            const char* rb_ = (const char*)h_lds + rowa * 1024;
#pragma unroll
            for (int ks = 0; ks < 4; ++ks) {
                a0 = MFMA(*(const short8*)(rb_ + ((kb0 + (4 * ks + 0) * 64) ^ sw)), wf[4 * ks + 0], a0);
                a1 = MFMA(*(const short8*)(rb_ + ((kb0 + (4 * ks + 1) * 64) ^ sw)), wf[4 * ks + 1], a1);
                a2 = MFMA(*(const short8*)(rb_ + ((kb0 + (4 * ks + 2) * 64) ^ sw)), wf[4 * ks + 2], a2);
                a3 = MFMA(*(const short8*)(rb_ + ((kb0 + (4 * ks + 3) * 64) ^ sw)), wf[4 * ks + 3], a3);
            }
        }
        f32x4 acc = (a0 + a1) + (a2 + a3);
#pragma unroll
        for (int i = 0; i < 4; ++i)
            g_buf[lc * 17 + ((lane >> 4) * 4 + i)] = acc[i] + gxv[i];
        __syncthreads();
        // gates + state update; publish FIRST (latency-critical), rout after
        {
            float iv = g_buf[jj * 17 + b_own];
            float fv = g_buf[(jj + 32) * 17 + b_own];
            float gv = g_buf[(jj + 64) * 17 + b_own];
            float ov = g_buf[(jj + 96) * 17 + b_own];
            cst = sigm(fv) * cst + sigm(iv) * tanh_f(gv);
            float h = sigm(ov) * tanh_f(cst);
            u16 hb = f2bf(h);
            u32* pp = hex_g + (u32)((t + 1) & 1) * 8192u + pub_idx;
            cstore1(pp, ((u32)(t + 1) << 16) | (u32)hb);
            rout[((size_t)(grp * 16 + b_own) * 1024 + t) * 512 + sl * 32 + jj] = hb;
        }
    }
}

// ---------- launch ----------
extern "C" void kernel_launch(void* const* d_in, const int* in_sizes, int n_in,
                              void* d_out, int out_size, void* d_ws, size_t ws_size,
                              hipStream_t stream) {
    const float* x     = (const float*)d_in[0];
    const float* pre_g = (const float*)d_in[1];
    const float* pre_b = (const float*)d_in[2];
    const float* w_ih  = (const float*)d_in[3];
    const float* w_hh  = (const float*)d_in[4];
    const float* b_ih  = (const float*)d_in[5];
    const float* b_hh  = (const float*)d_in[6];
    const float* post_g= (const float*)d_in[7];
    const float* post_b= (const float*)d_in[8];
    const float* w1    = (const float*)d_in[9];
    const float* b1    = (const float*)d_in[10];
    const float* w2    = (const float*)d_in[11];
    const float* b2    = (const float*)d_in[12];
    float* out = (float*)d_out;

    char* p = (char*)d_ws;
    auto carve = [&](size_t bytes) { void* r = (void*)p; p += (bytes + 255) & ~(size_t)255; return r; };
    u16* xln   = (u16*)carve(64ull * 1024 * 512 * 2);    // 64 MiB; reused as ln1 after GEMM1
    u16* gxb   = (u16*)carve(64ull * 1024 * 2048 * 2);   // 256 MiB; reused as h1 after scan
    u16* rb    = (u16*)carve(64ull * 1024 * 512 * 2);    // 64 MiB
    u16* wihb  = (u16*)carve(2048ull * 512 * 2);
    u16* whhb  = (u16*)carve(2048ull * 512 * 2);
    u16* w1t   = (u16*)carve(1024ull * 512 * 2);
    u16* w2t   = (u16*)carve(512ull * 1024 * 2);
    float* biasc = (float*)carve(2048ull * 4);
    u32* h_ex  = (u32*)carve(65536ull * 4);              // 4 groups x 2 parities x 8192 tagged u32
    u16* ln1 = xln;   // alias: xln dead after GEMM1
    u16* h1  = gxb;   // alias: gx dead after scan

    k_prep<<<3072, 256, 0, stream>>>(w_ih, w_hh, b_ih, b_hh, w1, w2, wihb, whhb, w1t, w2t, biasc);
    k_init<<<256, 256, 0, stream>>>(h_ex);
    k_pre_ln<<<16384, 256, 0, stream>>>(x, pre_g, pre_b, xln);
    k_gemm<512, 0><<<dim3(16, 512), 256, 0, stream>>>(xln, wihb, biasc, gxb, nullptr, nullptr, nullptr, 2048);
    k_scan<<<64, 512, 0, stream>>>(gxb, whhb, rb, h_ex);
    k_res_ln<<<16384, 256, 0, stream>>>(x, rb, post_g, post_b, ln1);
    k_gemm<512, 1><<<dim3(8, 512), 256, 0, stream>>>(ln1, w1t, b1, h1, nullptr, nullptr, nullptr, 1024);
    k_gemm<1024, 2><<<dim3(4, 512), 256, 0, stream>>>(h1, w2t, b2, nullptr, out, x, rb, 512);
}